// Round 7
// baseline (405.857 us; speedup 1.0000x reference)
//
#include <hip/hip_runtime.h>
#include <hip/hip_bf16.h>
#include <stdint.h>

typedef short bhalf8 __attribute__((ext_vector_type(8)));
typedef float facc4 __attribute__((ext_vector_type(4)));

static __device__ __forceinline__ unsigned short f2bfu(float f) {
  return __builtin_bit_cast(unsigned short, __float2bfloat16(f));
}

// ---------------------------------------------------------------------------
// prep: sample conv weights w = loc + L@eps (L = tril(-1)+softplus(diag)*I)
// bf16 layout wt[a=kh*3+kw][kc=i>>5][o][i&31], bias, 16-short zero pad.
// ---------------------------------------------------------------------------
__global__ void prep_kernel(const float* __restrict__ wloc,
                            const float* __restrict__ wL,
                            const float* __restrict__ eps_w,
                            const float* __restrict__ bloc,
                            const float* __restrict__ bro,
                            const float* __restrict__ eps_b,
                            short* __restrict__ wt, float* __restrict__ bias,
                            short* __restrict__ zeros) {
  int t = blockIdx.x * 256 + threadIdx.x;  // t = o*64 + i
  int o = t >> 6, i = t & 63;
  int kc = i >> 5, il = i & 31;
  const float* Lp = wL + (size_t)t * 81;
  const float* ep = eps_w + (size_t)t * 9;
  const float* lp = wloc + (size_t)t * 9;
  float e[9];
#pragma unroll
  for (int b = 0; b < 9; ++b) e[b] = ep[b];
#pragma unroll
  for (int a = 0; a < 9; ++a) {
    float s = lp[a];
    for (int b = 0; b < a; ++b) s += Lp[a * 9 + b] * e[b];
    float d = Lp[a * 9 + a];
    float sp = (d > 20.f) ? d : log1pf(expf(d));
    s += sp * e[a];
    wt[((a * 2 + kc) * 64 + o) * 32 + il] = (short)f2bfu(s);
  }
  if (t < 64) {
    float d = bro[t];
    float sp = (d > 20.f) ? d : log1pf(expf(d));
    bias[t] = bloc[t] + eps_b[t] * sp;
  }
  if (t < 16) zeros[t] = 0;
}

// ---------------------------------------------------------------------------
// pass 1: x NCHW f32 -> NHWC bf16 ([n][p=h*224+w][c64]). Streaming ~5.4 TB/s.
// ---------------------------------------------------------------------------
__global__ __launch_bounds__(512) void to_nhwc_kernel(
    const float* __restrict__ x, short* __restrict__ xh) {
  int b = blockIdx.x;
  int n = b / 196;
  int p0 = (b % 196) * 256;
  int t = threadIdx.x;
  int pl = t >> 3, c8 = t & 7;
  const float* xp = x + (size_t)(n * 64 + c8 * 8) * 50176 + p0 + pl * 4;
  short* op = xh + ((size_t)n * 50176 + p0 + pl * 4) * 64 + c8 * 8;
  float4 v[8];
#pragma unroll
  for (int j = 0; j < 8; ++j) v[j] = *(const float4*)(xp + (size_t)j * 50176);
#pragma unroll
  for (int s = 0; s < 4; ++s) {
    bhalf8 h;
#pragma unroll
    for (int j = 0; j < 8; ++j) h[j] = f2bfu(((const float*)&v[j])[s]);
    *(bhalf8*)(op + s * 64) = h;
  }
}

// ---------------------------------------------------------------------------
// pass 2: deep-pipelined 3x3 SAME conv (T3+T4). Block = 8 waves, tile
// 64o x 8r x 64px, loops 4 n x 2 ic = 8 rounds. Weights in LDS (73.7 KB,
// staged once); x-tile double-buffered (2 x 42.2 KB). Per round: 6 uniform
// global_load_lds issues/wave prefetch round j+1; s_waitcnt vmcnt(6) (never
// 0 mid-loop) + raw s_barrier -> prefetch stays in flight across barriers.
// Dynamic LDS 158.2 KB (<=160 KB/CU), 1 block/CU, in-block pipelining.
// ---------------------------------------------------------------------------
#define XCH 21120  // shorts per x buffer (2640 chunks * 8)

__global__ __launch_bounds__(512, 2) void conv_deep_kernel(
    const short* __restrict__ xh, const short* __restrict__ wtg,
    const float* __restrict__ bias, const short* __restrict__ zeros,
    float* __restrict__ out) {
  extern __shared__ short smem[];
  short* lds_wt = smem;           // 36864 shorts = 73728 B
  short* lds_x = smem + 36864;    // 2 * 21120 shorts = 84480 B

  int b0 = blockIdx.x;
  int b = (b0 & 7) * 112 + (b0 >> 3);  // XCD chunk; 896 % 8 == 0 bijective
  int nc = b / 112;
  int rem = b % 112;
  int w4 = rem / 28, ht = rem % 28;  // consecutive b -> adjacent ht
  int h0 = ht * 8, w0 = w4 * 64;
  int n0 = nc * 4;
  int t = threadIdx.x, lane = t & 63, wv = t >> 6;
  int l15 = lane & 15, l4 = lane >> 4;

  // --- precompute per-(k,lane) stage source offsets (round-invariant) ---
  int pre_off[6];
#pragma unroll
  for (int k = 0; k < 6; ++k) {
    int idx = k * 64 + lane;
    int c = wv * 330 + idx;
    int cc = c % 66;
    int rg = c / 66;
    int r = rg >> 2, g = rg & 3;
    int h_in = h0 - 1 + r, w_in = w0 - 1 + cc;
    bool ok = (idx < 330) & (h_in >= 0) & (h_in < 224) & (w_in >= 0) &
              (w_in < 224);
    pre_off[k] = ok ? ((h_in * 224 + w_in) * 64 + g * 8) : -1;
  }

  facc4 acc[4][4];
#pragma unroll
  for (int om = 0; om < 4; ++om)
#pragma unroll
    for (int p = 0; p < 4; ++p) {
      facc4 z = {0.f, 0.f, 0.f, 0.f};
      acc[om][p] = z;
    }

#define STAGE_X(bufsel, n_, ic_)                                              \
  do {                                                                        \
    const size_t nb = (size_t)(n_) * 50176 * 64 + (size_t)(ic_) * 32;         \
    _Pragma("unroll") for (int k = 0; k < 6; ++k) {                           \
      if (k * 64 + lane < 330) {                                              \
        const short* src = (pre_off[k] >= 0) ? xh + nb + pre_off[k] : zeros;  \
        __builtin_amdgcn_global_load_lds(                                     \
            (const __attribute__((address_space(1))) void*)src,               \
            (__attribute__((address_space(3))) void*)(lds_x +                 \
                                                      (bufsel)*XCH +          \
                                                      (wv * 330 + k * 64) *   \
                                                          8),                 \
            16, 0, 0);                                                        \
      }                                                                       \
    }                                                                         \
  } while (0)

  // --- prologue: stage weights (9 uniform issues/wave) + x round 0 ---
#pragma unroll
  for (int k = 0; k < 9; ++k) {
    int c = wv * 576 + k * 64 + lane;  // 4608 chunks total
    __builtin_amdgcn_global_load_lds(
        (const __attribute__((address_space(1))) void*)(wtg + c * 8),
        (__attribute__((address_space(3))) void*)(lds_wt +
                                                  (wv * 576 + k * 64) * 8),
        16, 0, 0);
  }
  STAGE_X(0, n0, 0);
  asm volatile("s_waitcnt vmcnt(0)" ::: "memory");
  __builtin_amdgcn_sched_barrier(0);
  __builtin_amdgcn_s_barrier();
  __builtin_amdgcn_sched_barrier(0);

  // --- 8 rounds: j -> n = n0 + (j>>1), ic = j&1 ---
#pragma unroll
  for (int j = 0; j < 8; ++j) {
    const int ic = j & 1;
    const int nn = n0 + (j >> 1);
    // prefetch next round
    if (j < 7) STAGE_X((j + 1) & 1, n0 + ((j + 1) >> 1), (j + 1) & 1);
    __builtin_amdgcn_sched_barrier(0);
    if (j < 7)
      asm volatile("s_waitcnt vmcnt(6)" ::: "memory");
    else
      asm volatile("s_waitcnt vmcnt(0)" ::: "memory");
    __builtin_amdgcn_sched_barrier(0);
    __builtin_amdgcn_s_barrier();
    __builtin_amdgcn_sched_barrier(0);

    const short* buf = lds_x + (j & 1) * XCH;
#pragma unroll
    for (int kh = 0; kh < 3; ++kh) {
      int r = wv + kh;
#pragma unroll
      for (int kw = 0; kw < 3; ++kw) {
        const int tap = kh * 3 + kw;
        bhalf8 a[4];
#pragma unroll
        for (int om = 0; om < 4; ++om)
          a[om] = *(const bhalf8*)(lds_wt +
                                   ((tap * 2 + ic) * 64 + om * 16 + l15) * 32 +
                                   (l4 << 3));
#pragma unroll
        for (int p = 0; p < 4; ++p) {
          int tc = p * 16 + l15 + kw;
          bhalf8 bv = *(const bhalf8*)(buf + ((r * 4 + l4) * 66 + tc) * 8);
#pragma unroll
          for (int om = 0; om < 4; ++om)
            acc[om][p] = __builtin_amdgcn_mfma_f32_16x16x32_bf16(
                a[om], bv, acc[om][p], 0, 0, 0);
        }
      }
    }

    if (ic == 1) {
      // epilogue for n = nn, then reset acc
      int h = h0 + wv;
#pragma unroll
      for (int om = 0; om < 4; ++om) {
#pragma unroll
        for (int jj = 0; jj < 4; ++jj) {
          int o = om * 16 + l4 * 4 + jj;
          float bo = bias[o];
          float* op = out + ((size_t)(nn * 64 + o) * 224 + h) * 224 + w0;
#pragma unroll
          for (int p = 0; p < 4; ++p) {
            int wg = w0 + p * 16 + l15;
            if (wg < 224) op[p * 16 + l15] = acc[om][p][jj] + bo;
          }
        }
      }
#pragma unroll
      for (int om = 0; om < 4; ++om)
#pragma unroll
        for (int p = 0; p < 4; ++p) {
          facc4 z = {0.f, 0.f, 0.f, 0.f};
          acc[om][p] = z;
        }
    }
    __builtin_amdgcn_s_barrier();  // all reads of buf[j&1] done
    __builtin_amdgcn_sched_barrier(0);
  }
#undef STAGE_X
}

// ---------------------------------------------------------------------------
// fallback (ws too small): R5 one-pass kernel (proven, 460 us).
// ---------------------------------------------------------------------------
typedef unsigned int uintv2 __attribute__((ext_vector_type(2)));
#define LD1(cj, i)                                                   \
  ((hok && (w_in0 + (i)) >= 0 && (w_in0 + (i)) < 224)                \
       ? cbase[(size_t)(cj) * 50176 + w_in0 + (i)]                   \
       : 0.f)

__global__ __launch_bounds__(256, 4) void conv_onepass_kernel(
    const float* __restrict__ x, const short* __restrict__ wt,
    const float* __restrict__ bias, float* __restrict__ out) {
  __shared__ short lds[6 * 66 * 32];
  int b0 = blockIdx.x;
  int b = (b0 & 7) * 896 + (b0 >> 3);
  int ht = b % 56;
  int rest = b / 56;
  int w4 = rest & 3, n = rest >> 2;
  int h0 = ht * 4, w0 = w4 * 64;
  int t = threadIdx.x, lane = t & 63, wv = t >> 6;
  int l15 = lane & 15, l4 = lane >> 4;

  facc4 acc[4][4];
#pragma unroll
  for (int om = 0; om < 4; ++om)
#pragma unroll
    for (int p = 0; p < 4; ++p) {
      facc4 z = {0.f, 0.f, 0.f, 0.f};
      acc[om][p] = z;
    }

  for (int ic = 0; ic < 2; ++ic) {
#pragma unroll
    for (int k = 0; k < 4; ++k) {
      int u = t + k * 256;
      if (u < 816) {
        int chg = u & 7;
        int tmp = u >> 3;
        int ccg = tmp % 17, r = tmp / 17;
        int h_in = h0 - 1 + r;
        bool hok = (h_in >= 0) & (h_in < 224);
        int w_in0 = w0 - 1 + ccg * 4;
        int ch0 = ic * 32 + chg * 4;
        const float* cbase =
            x + ((size_t)(n * 64 + ch0) * 224 + (hok ? h_in : 0)) * 224;
        float4 v0, v1, v2, v3;
        if (hok && w_in0 >= 0 && w_in0 + 3 < 224) {
          v0 = *(const float4*)(cbase + w_in0);
          v1 = *(const float4*)(cbase + 50176 + w_in0);
          v2 = *(const float4*)(cbase + 2 * 50176 + w_in0);
          v3 = *(const float4*)(cbase + 3 * 50176 + w_in0);
        } else {
          v0 = make_float4(LD1(0, 0), LD1(0, 1), LD1(0, 2), LD1(0, 3));
          v1 = make_float4(LD1(1, 0), LD1(1, 1), LD1(1, 2), LD1(1, 3));
          v2 = make_float4(LD1(2, 0), LD1(2, 1), LD1(2, 2), LD1(2, 3));
          v3 = make_float4(LD1(3, 0), LD1(3, 1), LD1(3, 2), LD1(3, 3));
        }
        int g = chg >> 1;
        int halfsel = (chg & 1) << 2;
#pragma unroll
        for (int i = 0; i < 4; ++i) {
          int cc = ccg * 4 + i;
          if (cc < 66) {
            float a0 = ((const float*)&v0)[i], a1 = ((const float*)&v1)[i];
            float a2 = ((const float*)&v2)[i], a3 = ((const float*)&v3)[i];
            unsigned int w0p =
                (unsigned int)f2bfu(a0) | ((unsigned int)f2bfu(a1) << 16);
            unsigned int w1p =
                (unsigned int)f2bfu(a2) | ((unsigned int)f2bfu(a3) << 16);
            int addr =
                (r * 66 + cc) * 32 + ((g ^ ((cc >> 1) & 3)) << 3) + halfsel;
            uintv2 pk = {w0p, w1p};
            *(uintv2*)(lds + addr) = pk;
          }
        }
      }
    }
    __syncthreads();
#pragma unroll
    for (int kh = 0; kh < 3; ++kh) {
      int r = wv + kh;
#pragma unroll
      for (int kw = 0; kw < 3; ++kw) {
        const short* wb =
            wt + (((kh * 3 + kw) * 2 + ic) * 64 + l15) * 32 + (l4 << 3);
        bhalf8 a[4];
#pragma unroll
        for (int om = 0; om < 4; ++om)
          a[om] = *(const bhalf8*)(wb + om * 512);
#pragma unroll
        for (int p = 0; p < 4; ++p) {
          int tc = p * 16 + l15 + kw;
          bhalf8 bv = *(const bhalf8*)(lds + (r * 66 + tc) * 32 +
                                       ((l4 ^ ((tc >> 1) & 3)) << 3));
#pragma unroll
          for (int om = 0; om < 4; ++om)
            acc[om][p] = __builtin_amdgcn_mfma_f32_16x16x32_bf16(
                a[om], bv, acc[om][p], 0, 0, 0);
        }
      }
    }
    if (ic == 0) __syncthreads();
  }

  int h = h0 + wv;
#pragma unroll
  for (int om = 0; om < 4; ++om) {
#pragma unroll
    for (int j = 0; j < 4; ++j) {
      int o = om * 16 + l4 * 4 + j;
      float bo = bias[o];
      float* op = out + ((size_t)(n * 64 + o) * 224 + h) * 224 + w0;
#pragma unroll
      for (int p = 0; p < 4; ++p) {
        int wg = w0 + p * 16 + l15;
        if (wg < 224) op[p * 16 + l15] = acc[om][p][j] + bo;
      }
    }
  }
}

extern "C" void kernel_launch(void* const* d_in, const int* in_sizes, int n_in,
                              void* d_out, int out_size, void* d_ws,
                              size_t ws_size, hipStream_t stream) {
  const float* x = (const float*)d_in[0];
  const float* wloc = (const float*)d_in[1];
  const float* wL = (const float*)d_in[2];
  const float* bloc = (const float*)d_in[3];
  const float* bro = (const float*)d_in[4];
  const float* eps_w = (const float*)d_in[5];
  const float* eps_b = (const float*)d_in[6];
  float* outp = (float*)d_out;

  short* wt = (short*)d_ws;                      // 73728 B
  float* bias = (float*)((char*)d_ws + 73728);   // 64 f32
  short* zeros = (short*)((char*)d_ws + 73984);  // 16 bf16 zero pad
  short* xh = (short*)((char*)d_ws + 74240);     // 205.5 MB
  const size_t need = 74240ull + (size_t)32 * 50176 * 64 * 2;

  prep_kernel<<<16, 256, 0, stream>>>(wloc, wL, eps_w, bloc, bro, eps_b, wt,
                                      bias, zeros);
  if (ws_size >= need) {
    to_nhwc_kernel<<<32 * 196, 512, 0, stream>>>(x, xh);
    const int dyn_lds = (36864 + 2 * XCH) * 2;  // 158208 B
    hipFuncSetAttribute((const void*)conv_deep_kernel,
                        hipFuncAttributeMaxDynamicSharedMemorySize, dyn_lds);
    conv_deep_kernel<<<896, 512, dyn_lds, stream>>>(xh, wt, bias, zeros, outp);
  } else {
    conv_onepass_kernel<<<7168, 256, 0, stream>>>(x, wt, bias, outp);
  }
}